// Round 1
// 5215.616 us; speedup vs baseline: 1.3671x; 1.3671x over previous
//
#include <hip/hip_runtime.h>
#include <stdint.h>

#define H   512
#define B   64
#define T   512
#define E   256
#define G3  1536   // 3*H
#define CT  64     // time-chunk length (T/CT = 8 chunks)
#define NBG 4      // independent batch groups (16 batches each)
#define NUG 32     // unit waves per direction (16 units each)

typedef short s16;
typedef unsigned short u16;
typedef __attribute__((ext_vector_type(8))) short   short8;
typedef __attribute__((ext_vector_type(4))) float   f32x4;
typedef __attribute__((ext_vector_type(4))) unsigned int u32x4;
typedef __bf16 bf8_t __attribute__((ext_vector_type(8)));

__device__ __forceinline__ u16 f2b(float f) {
    union { float f; unsigned int i; } v; v.f = f;
    unsigned int r = v.i + 0x7FFF + ((v.i >> 16) & 1);
    return (u16)(r >> 16);
}
__device__ __forceinline__ float sigm(float x)  { return 1.f / (1.f + __expf(-x)); }
__device__ __forceinline__ float tanhs(float x) { return 1.f - 2.f / (1.f + __expf(2.f * x)); }

// ------------------------------------------------------- fp32 -> bf16 weight convert
__global__ void k_cvt(const float* __restrict__ src, u16* __restrict__ dst, int n) {
    int i = blockIdx.x * 256 + threadIdx.x;
    int stride = gridDim.x * 256;
    for (; i < n; i += stride) dst[i] = f2b(src[i]);
}

// ------------------------------------------------------- init h32/hbf/flags
__global__ void k_init(float* __restrict__ h32, u16* __restrict__ hbf, int* __restrict__ bar) {
    int i = blockIdx.x * 256 + threadIdx.x;      // 131072 = 2 dirs * 2 slices * B*H
    hbf[i] = 0;
    if (i < 65536) h32[i] = 0.f;                 // 2 dirs * B*H carry
    if (i < 4096)  bar[i] = 0;                   // 2*4*32 flags, 16-int (64B) stride
}

// ------------------------------------------------------- xg chunk GEMM (MFMA)
// Writes xgT[d][tl][n][b] (fp32) = A[b,t,:K] . Wbf[d][n][:K] + bih[d][n]
// row m of the M=4096 tile: b=m>>6, tl=m&63; t = t0(d,c)+tl.
#define BM 128
#define BN 128
#define BK 32

__global__ __launch_bounds__(256)
void k_gemm_xg(const int* __restrict__ sent, const void* __restrict__ Abuf, int aIsF32,
               const u16* __restrict__ Wbf, const float* __restrict__ bih,
               float* __restrict__ xgT, int K, int c) {
    int d  = blockIdx.z;
    int t0 = d ? (T - (c + 1) * CT) : c * CT;
    const u16* Bw = Wbf + (long)d * G3 * K;
    const float* bias = bih + (long)d * G3;
    float* C = xgT + (long)d * (long)CT * G3 * B;

    __shared__ __align__(16) s16 lA[BM * BK];
    __shared__ __align__(16) s16 lB[BN * BK];

    int tid  = threadIdx.x;
    int lane = tid & 63;
    int wv   = tid >> 6;
    int wm   = wv >> 1, wn = wv & 1;
    int q    = lane >> 4, r16 = lane & 15;

    long m0 = (long)blockIdx.x * BM;
    long n0 = (long)blockIdx.y * BN;

    const float* rowAf[2];
    const s16*   rowAh[2];
    const u16*   rowB[2];
    #pragma unroll
    for (int i = 0; i < 2; i++) {
        int ch = tid + i * 256;
        int r  = ch >> 2, cc = (ch & 3) * 8;
        long m = m0 + r;
        int  bb_ = (int)(m >> 6), tl = (int)(m & 63);
        int  t  = t0 + tl;
        if (aIsF32) rowAf[i] = (const float*)Abuf + (long)sent[bb_ * T + t] * K + cc;
        else        rowAh[i] = (const s16*)Abuf + ((long)bb_ * T + t) * K + cc;
        rowB[i] = Bw + (n0 + r) * K + cc;
    }

    f32x4 acc[4][4];
    #pragma unroll
    for (int i = 0; i < 4; i++)
        #pragma unroll
        for (int j = 0; j < 4; j++) acc[i][j] = (f32x4){0.f, 0.f, 0.f, 0.f};

    for (long k0 = 0; k0 < K; k0 += BK) {
        #pragma unroll
        for (int i = 0; i < 2; i++) {
            if (aIsF32) {
                float4 v0 = *(const float4*)(rowAf[i] + k0);
                float4 v1 = *(const float4*)(rowAf[i] + k0 + 4);
                short8 pk;
                pk[0] = (s16)f2b(v0.x); pk[1] = (s16)f2b(v0.y);
                pk[2] = (s16)f2b(v0.z); pk[3] = (s16)f2b(v0.w);
                pk[4] = (s16)f2b(v1.x); pk[5] = (s16)f2b(v1.y);
                pk[6] = (s16)f2b(v1.z); pk[7] = (s16)f2b(v1.w);
                ((short8*)lA)[tid + i * 256] = pk;
            } else {
                ((short8*)lA)[tid + i * 256] = *(const short8*)(rowAh[i] + k0);
            }
            ((short8*)lB)[tid + i * 256] = *(const short8*)((const s16*)rowB[i] + k0);
        }
        __syncthreads();

        bf8_t af[4], bf[4];
        #pragma unroll
        for (int mt = 0; mt < 4; mt++)
            af[mt] = ((const bf8_t*)lA)[(wm * 64 + mt * 16 + r16) * 4 + q];
        #pragma unroll
        for (int nt = 0; nt < 4; nt++)
            bf[nt] = ((const bf8_t*)lB)[(wn * 64 + nt * 16 + r16) * 4 + q];
        #pragma unroll
        for (int mt = 0; mt < 4; mt++)
            #pragma unroll
            for (int nt = 0; nt < 4; nt++)
                acc[mt][nt] = __builtin_amdgcn_mfma_f32_16x16x32_bf16(
                                  af[mt], bf[nt], acc[mt][nt], 0, 0, 0);
        __syncthreads();
    }

    #pragma unroll
    for (int nt = 0; nt < 4; nt++) {
        long n = n0 + wn * 64 + nt * 16 + r16;
        float bv = bias[n];
        #pragma unroll
        for (int mt = 0; mt < 4; mt++) {
            #pragma unroll
            for (int rg = 0; rg < 4; rg++) {
                long m = m0 + wm * 64 + mt * 16 + q * 4 + rg;
                C[((long)(m & 63) * G3 + n) * B + (m >> 6)] = acc[mt][nt][rg] + bv;
            }
        }
    }
}

// ------------------------------------------------------- wave-autonomous chunk recurrence
// Grid (NUG=32, NBG=4, 2 dirs) x 64 thr: 256 single-wave blocks, all co-resident.
// The recurrence is batch-diagonal, so each (dir, batch-group) of 16 batches syncs
// only among its own 32 unit-waves (8 independent sync domains).
// Wave holds its 16-unit weight slice in REGISTERS (bf8_t w[3][16] = 192 VGPR):
// zero LDS and zero __syncthreads in the step loop.
// Cross-wave h state (hbf) via write-through (sc0 sc1) stores + monolithic
// cache-bypass load block. Barrier = distributed per-wave flag stores (own 64B
// line each, no RMW) + wave-wide vector poll with __all.
__global__ __launch_bounds__(64, 1)
void k_chunk(const u16* __restrict__ Whhbf, const float* __restrict__ bhh,
             const float* __restrict__ xgT, float* __restrict__ h32,
             u16* __restrict__ hbf, int c, u16* __restrict__ x1out, int writeX1,
             int* __restrict__ flags) {
    int ug = blockIdx.x;                 // unit group: units ug*16..+15
    int bg = blockIdx.y;                 // batch group: batches bg*16..+15
    int d  = blockIdx.z;
    int lane = threadIdx.x;              // 0..63
    int q = lane >> 4, cc = lane & 15;
    int u0 = ug * 16;
    int u  = u0 + cc;

    const u16* W    = Whhbf + (long)d * G3 * H;
    const float* bb = bhh + (long)d * G3;
    const float* xgf = xgT + (long)d * (long)CT * G3 * B;
    float* h32d = h32 + (long)d * B * H;
    u16*   hbfd = hbf + (long)d * 2 * B * H;
    int*   fgrp   = flags + (d * NBG + bg) * NUG * 16;   // this domain's 32 flags
    int*   myflag = fgrp + ug * 16;
    const int* fpoll = fgrp + (lane & 31) * 16;

    // ---- weight slice into registers: w[gate][kc] is the MFMA B-frag ----
    // B-frag layout: lane holds B[col=lane&15][k = (lane>>4)*8 .. +7] of the K=32 tile.
    bf8_t w[3][16];
    #pragma unroll
    for (int gate = 0; gate < 3; gate++)
        #pragma unroll
        for (int kc = 0; kc < 16; kc++)
            w[gate][kc] = *(const bf8_t*)(W + (long)(gate * H + u0 + cc) * H + kc * 32 + q * 8);

    float br = bb[u], bz = bb[H + u], bn = bb[2 * H + u];

    // fp32 h-carry: lane holds h[b = bg*16 + q*4 + rg][u]
    float hp[4];
    #pragma unroll
    for (int rg = 0; rg < 4; rg++)
        hp[rg] = h32d[(long)(bg * 16 + q * 4 + rg) * H + u];

    int base = c * CT;
    int bA = bg * 16 + cc;               // A-frag row (m = lane&15) = batch

    for (int sl = 0; sl < CT; sl++) {
        int s    = base + sl;
        int tl   = d ? (CT - 1 - sl) : sl;
        int time = d ? (T - 1 - s) : s;

        // xg vector loads (normal cached; issued before the bypass block, overlap it)
        long xb = ((long)tl * G3 + u) * B + (bg * 16 + q * 4);
        f32x4 xrv = *(const f32x4*)(xgf + xb);
        f32x4 xzv = *(const f32x4*)(xgf + xb + (long)H * B);
        f32x4 xnv = *(const f32x4*)(xgf + xb + (long)2 * H * B);

        // A-fragments: one monolithic bypass-load block (internal waitcnt).
        const u16* hq = hbfd + (long)(s & 1) * B * H + (long)bA * H + q * 8;
        u32x4 a0,a1,a2,a3,a4,a5,a6,a7,a8,a9,a10,a11,a12,a13,a14,a15;
        asm volatile(
            "global_load_dwordx4 %0,  %16, off sc0 sc1\n\t"
            "global_load_dwordx4 %1,  %16, off offset:64  sc0 sc1\n\t"
            "global_load_dwordx4 %2,  %16, off offset:128 sc0 sc1\n\t"
            "global_load_dwordx4 %3,  %16, off offset:192 sc0 sc1\n\t"
            "global_load_dwordx4 %4,  %16, off offset:256 sc0 sc1\n\t"
            "global_load_dwordx4 %5,  %16, off offset:320 sc0 sc1\n\t"
            "global_load_dwordx4 %6,  %16, off offset:384 sc0 sc1\n\t"
            "global_load_dwordx4 %7,  %16, off offset:448 sc0 sc1\n\t"
            "global_load_dwordx4 %8,  %16, off offset:512 sc0 sc1\n\t"
            "global_load_dwordx4 %9,  %16, off offset:576 sc0 sc1\n\t"
            "global_load_dwordx4 %10, %16, off offset:640 sc0 sc1\n\t"
            "global_load_dwordx4 %11, %16, off offset:704 sc0 sc1\n\t"
            "global_load_dwordx4 %12, %16, off offset:768 sc0 sc1\n\t"
            "global_load_dwordx4 %13, %16, off offset:832 sc0 sc1\n\t"
            "global_load_dwordx4 %14, %16, off offset:896 sc0 sc1\n\t"
            "global_load_dwordx4 %15, %16, off offset:960 sc0 sc1\n\t"
            "s_waitcnt vmcnt(0)"
            : "=&v"(a0),"=&v"(a1),"=&v"(a2),"=&v"(a3),
              "=&v"(a4),"=&v"(a5),"=&v"(a6),"=&v"(a7),
              "=&v"(a8),"=&v"(a9),"=&v"(a10),"=&v"(a11),
              "=&v"(a12),"=&v"(a13),"=&v"(a14),"=&v"(a15)
            : "v"(hq)
            : "memory");
        bf8_t af[16];
        af[0]=__builtin_bit_cast(bf8_t,a0);   af[1]=__builtin_bit_cast(bf8_t,a1);
        af[2]=__builtin_bit_cast(bf8_t,a2);   af[3]=__builtin_bit_cast(bf8_t,a3);
        af[4]=__builtin_bit_cast(bf8_t,a4);   af[5]=__builtin_bit_cast(bf8_t,a5);
        af[6]=__builtin_bit_cast(bf8_t,a6);   af[7]=__builtin_bit_cast(bf8_t,a7);
        af[8]=__builtin_bit_cast(bf8_t,a8);   af[9]=__builtin_bit_cast(bf8_t,a9);
        af[10]=__builtin_bit_cast(bf8_t,a10); af[11]=__builtin_bit_cast(bf8_t,a11);
        af[12]=__builtin_bit_cast(bf8_t,a12); af[13]=__builtin_bit_cast(bf8_t,a13);
        af[14]=__builtin_bit_cast(bf8_t,a14); af[15]=__builtin_bit_cast(bf8_t,a15);

        f32x4 aR = (f32x4){0.f,0.f,0.f,0.f};
        f32x4 aZ = (f32x4){0.f,0.f,0.f,0.f};
        f32x4 aN = (f32x4){0.f,0.f,0.f,0.f};
        #pragma unroll
        for (int kc = 0; kc < 16; kc++) {
            aR = __builtin_amdgcn_mfma_f32_16x16x32_bf16(af[kc], w[0][kc], aR, 0, 0, 0);
            aZ = __builtin_amdgcn_mfma_f32_16x16x32_bf16(af[kc], w[1][kc], aZ, 0, 0, 0);
            aN = __builtin_amdgcn_mfma_f32_16x16x32_bf16(af[kc], w[2][kc], aN, 0, 0, 0);
        }

        u16* hnb = hbfd + (long)((s + 1) & 1) * B * H;
        #pragma unroll
        for (int rg = 0; rg < 4; rg++) {
            int b = bg * 16 + q * 4 + rg;         // D layout: m = (lane>>4)*4+reg
            float r = sigm(xrv[rg] + aR[rg] + br);
            float z = sigm(xzv[rg] + aZ[rg] + bz);
            float n = tanhs(xnv[rg] + r * (aN[rg] + bn));
            float hh = (1.f - z) * n + z * hp[rg];
            hp[rg] = hh;
            u16 hv = f2b(hh);
            asm volatile("global_store_short %0, %1, off sc0 sc1"
                         :: "v"(hnb + (long)b * H + u), "v"((unsigned int)hv) : "memory");
            if (writeX1)
                x1out[((long)b * T + time) * 1024 + d * H + u] = hv;
        }

        // drain this wave's stores (WT ack => device-visible), then flag + poll.
        asm volatile("s_waitcnt vmcnt(0)" ::: "memory");
        if (sl < CT - 1) {
            int tgt = s + 1;
            if (lane == 0)
                asm volatile("global_store_dword %0, %1, off sc0 sc1"
                             :: "v"(myflag), "v"(tgt) : "memory");
            int v;
            do {
                asm volatile("global_load_dword %0, %1, off sc0 sc1\n\t"
                             "s_waitcnt vmcnt(0)"
                             : "=v"(v) : "v"(fpoll) : "memory");
            } while (!__all(v >= tgt));
        }
        // last step: no flag/poll — next dispatch is stream-ordered (kernel boundary).
    }

    // spill fp32 carry for next chunk dispatch / k_fc (kernel-boundary coherence)
    #pragma unroll
    for (int rg = 0; rg < 4; rg++)
        h32d[(long)(bg * 16 + q * 4 + rg) * H + u] = hp[rg];
}

// ------------------------------------------------------- final FC (fp32)
__global__ __launch_bounds__(256)
void k_fc(const float* __restrict__ h32, const float* __restrict__ fcw,
          const float* __restrict__ fcb, float* __restrict__ out) {
    int b   = blockIdx.x;
    int tid = threadIdx.x;
    float p[10];
    #pragma unroll
    for (int o = 0; o < 10; o++) p[o] = 0.f;
    for (int k = tid; k < 1024; k += 256) {
        int dd = k >> 9, kk = k & 511;
        float hv = h32[(long)dd * B * H + (long)b * H + kk];
        #pragma unroll
        for (int o = 0; o < 10; o++) p[o] += hv * fcw[o * 1024 + k];
    }
    __shared__ float red[10][256];
    #pragma unroll
    for (int o = 0; o < 10; o++) red[o][tid] = p[o];
    __syncthreads();
    for (int off = 128; off > 0; off >>= 1) {
        if (tid < off)
            #pragma unroll
            for (int o = 0; o < 10; o++) red[o][tid] += red[o][tid + off];
        __syncthreads();
    }
    if (tid < 10) out[b * 10 + tid] = red[tid][0] + fcb[tid];
}

// ------------------------------------------------------- launcher
extern "C" void kernel_launch(void* const* d_in, const int* in_sizes, int n_in,
                              void* d_out, int out_size, void* d_ws, size_t ws_size,
                              hipStream_t stream) {
    const int*   sent = (const int*)d_in[0];
    const float* emb  = (const float*)d_in[1];
    const float* wih0 = (const float*)d_in[2];
    const float* whh0 = (const float*)d_in[3];
    const float* bih0 = (const float*)d_in[4];
    const float* bhh0 = (const float*)d_in[5];
    const float* wih1 = (const float*)d_in[6];
    const float* whh1 = (const float*)d_in[7];
    const float* bih1 = (const float*)d_in[8];
    const float* bhh1 = (const float*)d_in[9];
    const float* fcw  = (const float*)d_in[10];
    const float* fcb  = (const float*)d_in[11];
    float* outp = (float*)d_out;

    // workspace layout — ~132.2 MB (proven-safe envelope: >=134.5 MB)
    char*  ws  = (char*)d_ws;
    float* xg  = (float*)(ws);                           // 2*CT*G3*B*4 = 50,331,648 B
    u16*   x1  = (u16*)(ws + 50331648L);                 // B*T*1024*2  = 67,108,864 B
    float* h32 = (float*)(ws + 50331648L + 67108864L);   // 2*B*H*4     =    262,144 B
    u16*   hbf = (u16*)(ws + 50331648L + 67108864L + 262144L);   // 262,144 B
    int*   bar = (int*)(ws + 50331648L + 67108864L + 262144L + 262144L); // 16,384 B flags
    u16*   wbf = (u16*)(ws + 50331648L + 67108864L + 262144L + 262144L + 16384L);
    u16* wih0b = wbf;                      // 2*1536*256  =   786,432 el
    u16* wih1b = wbf + 786432L;            // 2*1536*1024 = 3,145,728 el
    u16* whh0b = wbf + 786432L + 3145728L; // 2*1536*512  = 1,572,864 el
    u16* whh1b = whh0b + 1572864L;         // 1,572,864 el

    // convert weights fp32 -> bf16 (graph-safe, runs every launch)
    k_cvt<<<512, 256, 0, stream>>>(wih0, wih0b, 786432);
    k_cvt<<<512, 256, 0, stream>>>(wih1, wih1b, 3145728);
    k_cvt<<<512, 256, 0, stream>>>(whh0, whh0b, 1572864);
    k_cvt<<<512, 256, 0, stream>>>(whh1, whh1b, 1572864);

    dim3 gg(32, 12, 2);      // GEMM: 32 m-blocks x 12 n-tiles x 2 dirs
    dim3 gc(NUG, NBG, 2);    // recurrence: 32 unit-waves x 4 batch-groups x 2 dirs

    // ---- layer 0 (embedding gather fused into GEMM A-staging) ----
    k_init<<<512, 256, 0, stream>>>(h32, hbf, bar);
    for (int c = 0; c < T / CT; c++) {
        k_gemm_xg<<<gg, 256, 0, stream>>>(sent, emb, 1, wih0b, bih0, xg, E, c);
        k_chunk<<<gc, 64, 0, stream>>>(whh0b, bhh0, xg, h32, hbf, c, x1, 1, bar);
    }

    // ---- layer 1 (A = x1, already bf16) ----
    k_init<<<512, 256, 0, stream>>>(h32, hbf, bar);
    for (int c = 0; c < T / CT; c++) {
        k_gemm_xg<<<gg, 256, 0, stream>>>(sent, x1, 0, wih1b, bih1, xg, 2 * H, c);
        k_chunk<<<gc, 64, 0, stream>>>(whh1b, bhh1, xg, h32, hbf, c, (u16*)nullptr, 0, bar);
    }

    k_fc<<<B, 256, 0, stream>>>(h32, fcw, fcb, outp);
}